// Round 2
// baseline (519.958 us; speedup 1.0000x reference)
//
#include <hip/hip_runtime.h>
#include <math.h>

#define BQ 65536
#define NC 512
#define DD 512
#define BM 128
#define BN 256
#define BK 32
#define MARGIN 4e-3f

// LDS swizzle: spreads k into bank bits (write conflicts -> 2-way, free) and
// col-high bits into bank bits (b-frag ds_read_b128 -> <=2-way). Bits 0-1
// untouched so float4 groups stay contiguous.
__device__ __forceinline__ int swz(int idx, int k) {
    return idx ^ (((k >> 2) & 7) << 2) ^ (((idx >> 5) & 7) << 2);
}

// numpy-pairwise-order sum of squares over 128 elements (used for fp32 csq;
// accuracy only needs to be ~1e-6, exact order no longer matters).
__device__ __forceinline__ float pw128_sq(const float* __restrict__ p) {
    float r[8];
    #pragma unroll
    for (int j = 0; j < 8; ++j) r[j] = 0.0f;
    #pragma unroll
    for (int q = 0; q < 32; ++q) {
        float4 v = *(const float4*)(p + q * 4);
        const int e = (q & 1) << 2;
        r[e + 0] = __fadd_rn(r[e + 0], __fmul_rn(v.x, v.x));
        r[e + 1] = __fadd_rn(r[e + 1], __fmul_rn(v.y, v.y));
        r[e + 2] = __fadd_rn(r[e + 2], __fmul_rn(v.z, v.z));
        r[e + 3] = __fadd_rn(r[e + 3], __fmul_rn(v.w, v.w));
    }
    return __fadd_rn(__fadd_rn(__fadd_rn(r[0], r[1]), __fadd_rn(r[2], r[3])),
                     __fadd_rn(__fadd_rn(r[4], r[5]), __fadd_rn(r[6], r[7])));
}

// Pass 1: fp32 tiled GEMM computing metric m_j = csq[j] - 2*z.c_j per row,
// tracking best + second-best. Rows whose (b2-b1) gap < MARGIN go to a
// worklist for the fp64 fixup pass. z_sq dropped: constant per row, and
// sqrt is monotone -> argmin unaffected.
__global__ __launch_bounds__(256, 2) void codebook_kernel(
    const float* __restrict__ Z, const float* __restrict__ Cb,
    float* __restrict__ out, int* __restrict__ wslist, int cap) {

    __shared__ float smem[BK * BM + BK * BN + NC];  // As | Bs | csq
    __shared__ int bif[BM];
    float* As = smem;
    float* Bs = smem + BK * BM;
    float* csq = smem + BK * BM + BK * BN;

    const int tid = threadIdx.x;
    const int tx = tid & 15, ty = tid >> 4;
    const int m0 = blockIdx.x * BM;
    const int myrow0 = ty * 8;

    // csq for all 512 codes (codebook is L2-resident)
    #pragma unroll
    for (int cc = 0; cc < 2; ++cc) {
        const int code = tid + cc * 256;
        const float* p = Cb + (size_t)code * DD;
        float b0 = pw128_sq(p);
        float b1 = pw128_sq(p + 128);
        float b2 = pw128_sq(p + 256);
        float b3 = pw128_sq(p + 384);
        csq[code] = __fadd_rn(__fadd_rn(b0, b1), __fadd_rn(b2, b3));
    }

    float b1v[8], b2v[8]; int i1v[8];
    #pragma unroll
    for (int i = 0; i < 8; ++i) {
        b1v[i] = 3.402823466e38f; b2v[i] = 3.402823466e38f; i1v[i] = 0;
    }

    for (int chunk = 0; chunk < 2; ++chunk) {
        const int n0 = chunk * BN;
        float acc[8][16];
        #pragma unroll
        for (int i = 0; i < 8; ++i)
            #pragma unroll
            for (int j = 0; j < 16; ++j) acc[i][j] = 0.0f;

        for (int kt = 0; kt < DD; kt += BK) {
            __syncthreads();
            float4 va[4], vb[8];
            #pragma unroll
            for (int p = 0; p < 4; ++p) {
                int q = tid + p * 256;
                va[p] = *(const float4*)(Z + (size_t)(m0 + (q >> 3)) * DD + kt + (q & 7) * 4);
            }
            #pragma unroll
            for (int p = 0; p < 8; ++p) {
                int q = tid + p * 256;
                vb[p] = *(const float4*)(Cb + (size_t)(n0 + (q >> 3)) * DD + kt + (q & 7) * 4);
            }
            #pragma unroll
            for (int p = 0; p < 4; ++p) {
                int q = tid + p * 256;
                int r = q >> 3, k0 = (q & 7) * 4;
                As[(k0 + 0) * BM + swz(r, k0 + 0)] = va[p].x;
                As[(k0 + 1) * BM + swz(r, k0 + 1)] = va[p].y;
                As[(k0 + 2) * BM + swz(r, k0 + 2)] = va[p].z;
                As[(k0 + 3) * BM + swz(r, k0 + 3)] = va[p].w;
            }
            #pragma unroll
            for (int p = 0; p < 8; ++p) {
                int q = tid + p * 256;
                int r = q >> 3, k0 = (q & 7) * 4;
                Bs[(k0 + 0) * BN + swz(r, k0 + 0)] = vb[p].x;
                Bs[(k0 + 1) * BN + swz(r, k0 + 1)] = vb[p].y;
                Bs[(k0 + 2) * BN + swz(r, k0 + 2)] = vb[p].z;
                Bs[(k0 + 3) * BN + swz(r, k0 + 3)] = vb[p].w;
            }
            __syncthreads();

            #pragma unroll 4
            for (int k = 0; k < BK; ++k) {
                float4 a0 = *(const float4*)&As[k * BM + swz(myrow0, k)];
                float4 a1 = *(const float4*)&As[k * BM + swz(myrow0 + 4, k)];
                float4 q0 = *(const float4*)&Bs[k * BN + swz(tx * 16 + 0, k)];
                float4 q1 = *(const float4*)&Bs[k * BN + swz(tx * 16 + 4, k)];
                float4 q2 = *(const float4*)&Bs[k * BN + swz(tx * 16 + 8, k)];
                float4 q3 = *(const float4*)&Bs[k * BN + swz(tx * 16 + 12, k)];
                float av[8] = {a0.x, a0.y, a0.z, a0.w, a1.x, a1.y, a1.z, a1.w};
                float bv[16] = {q0.x, q0.y, q0.z, q0.w, q1.x, q1.y, q1.z, q1.w,
                                q2.x, q2.y, q2.z, q2.w, q3.x, q3.y, q3.z, q3.w};
                #pragma unroll
                for (int i = 0; i < 8; ++i)
                    #pragma unroll
                    for (int j = 0; j < 16; ++j)
                        acc[i][j] = fmaf(av[i], bv[j], acc[i][j]);
            }
        }

        // metric + best/second-best (codes ascending per thread)
        #pragma unroll
        for (int i = 0; i < 8; ++i) {
            #pragma unroll
            for (int j = 0; j < 16; ++j) {
                int code = n0 + tx * 16 + j;
                float m = csq[code] - 2.0f * acc[i][j];
                if (m < b1v[i]) { b2v[i] = b1v[i]; b1v[i] = m; i1v[i] = code; }
                else if (m < b2v[i]) { b2v[i] = m; }
            }
        }
    }

    // cross-thread (16 tx) reduction keeping best+second-best
    __syncthreads();
    float* red_b1 = smem;                          // [BM][17]
    int* red_i1 = (int*)(smem + BM * 17);          // [BM][17]
    float* red_b2 = smem + 2 * BM * 17;            // [BM][17]
    #pragma unroll
    for (int i = 0; i < 8; ++i) {
        red_b1[(myrow0 + i) * 17 + tx] = b1v[i];
        red_i1[(myrow0 + i) * 17 + tx] = i1v[i];
        red_b2[(myrow0 + i) * 17 + tx] = b2v[i];
    }
    __syncthreads();
    if (tid < BM) {
        float mb1 = red_b1[tid * 17]; int mi1 = red_i1[tid * 17];
        float mb2 = red_b2[tid * 17];
        #pragma unroll
        for (int t = 1; t < 16; ++t) {
            float c1 = red_b1[tid * 17 + t]; int ci = red_i1[tid * 17 + t];
            float c2 = red_b2[tid * 17 + t];
            if (c1 < mb1 || (c1 == mb1 && ci < mi1)) {
                mb2 = fminf(mb1, c2); mb1 = c1; mi1 = ci;
            } else {
                mb2 = fminf(mb2, c1);
            }
        }
        bif[tid] = mi1;
        out[(size_t)BQ * NC + m0 + tid] = (float)mi1;
        if (mb2 - mb1 < MARGIN) {               // knife-edge row -> fp64 pass
            int slot = atomicAdd(wslist, 1);
            if (slot < cap) wslist[1 + slot] = m0 + tid;
        }
    }
    __syncthreads();

    // one_hot: 128 rows x 512 cols, coalesced float4 stores
    #pragma unroll 4
    for (int t = 0; t < 64; ++t) {
        int f4i = tid + t * 256;
        int r = f4i >> 7, c4 = f4i & 127;
        int tgt = bif[r];
        int base = c4 * 4;
        float4 v;
        v.x = (tgt == base + 0) ? 1.0f : 0.0f;
        v.y = (tgt == base + 1) ? 1.0f : 0.0f;
        v.z = (tgt == base + 2) ? 1.0f : 0.0f;
        v.w = (tgt == base + 3) ? 1.0f : 0.0f;
        *(float4*)(out + (size_t)(m0 + r) * NC + (size_t)base) = v;
    }
}

// Pass 2: fp64-exact argmin for marginal rows. f64 FMA of promoted fp32
// inputs has exact products -> result matches numpy-fp64 argmin.
__global__ __launch_bounds__(256) void fixup_kernel(
    const float* __restrict__ Z, const float* __restrict__ Cb,
    float* __restrict__ out, const int* __restrict__ wslist, int cap) {

    __shared__ float zrow[DD];
    __shared__ double md[256];
    __shared__ int mi[256];
    const int tid = threadIdx.x;
    int count = wslist[0];
    if (count > cap) count = cap;

    for (int e = blockIdx.x; e < count; e += gridDim.x) {
        const int row = wslist[1 + e];
        zrow[tid] = Z[(size_t)row * DD + tid];
        zrow[tid + 256] = Z[(size_t)row * DD + 256 + tid];
        __syncthreads();

        double bb = 1e300; int bidx = 0;
        #pragma unroll
        for (int cc = 0; cc < 2; ++cc) {
            const int code = tid * 2 + cc;
            const float* cp = Cb + (size_t)code * DD;
            double dot = 0.0, cs = 0.0;
            for (int k = 0; k < DD; k += 4) {
                float4 c4 = *(const float4*)(cp + k);
                double a0 = (double)zrow[k + 0], c0 = (double)c4.x;
                double a1 = (double)zrow[k + 1], c1 = (double)c4.y;
                double a2 = (double)zrow[k + 2], c2 = (double)c4.z;
                double a3 = (double)zrow[k + 3], c3 = (double)c4.w;
                dot = fma(a0, c0, dot); cs = fma(c0, c0, cs);
                dot = fma(a1, c1, dot); cs = fma(c1, c1, cs);
                dot = fma(a2, c2, dot); cs = fma(c2, c2, cs);
                dot = fma(a3, c3, dot); cs = fma(c3, c3, cs);
            }
            double m = cs - 2.0 * dot;
            if (m < bb || (m == bb && code < bidx)) { bb = m; bidx = code; }
        }
        md[tid] = bb; mi[tid] = bidx;
        __syncthreads();
        for (int s = 128; s > 0; s >>= 1) {
            if (tid < s) {
                if (md[tid + s] < md[tid] ||
                    (md[tid + s] == md[tid] && mi[tid + s] < mi[tid])) {
                    md[tid] = md[tid + s]; mi[tid] = mi[tid + s];
                }
            }
            __syncthreads();
        }
        const int imin = mi[0];
        out[(size_t)row * NC + tid] = (tid == imin) ? 1.0f : 0.0f;
        out[(size_t)row * NC + 256 + tid] = (tid + 256 == imin) ? 1.0f : 0.0f;
        if (tid == 0) out[(size_t)BQ * NC + row] = (float)imin;
        __syncthreads();
    }
}

extern "C" void kernel_launch(void* const* d_in, const int* in_sizes, int n_in,
                              void* d_out, int out_size, void* d_ws, size_t ws_size,
                              hipStream_t stream) {
    const float* Z = (const float*)d_in[0];
    const float* Cb = (const float*)d_in[1];
    float* out = (float*)d_out;
    int* wslist = (int*)d_ws;
    int cap = (int)(ws_size / 4) - 1;
    if (cap > BQ) cap = BQ;
    hipMemsetAsync(d_ws, 0, 4, stream);  // zero worklist counter each launch
    codebook_kernel<<<dim3(BQ / BM), dim3(256), 0, stream>>>(Z, Cb, out, wslist, cap);
    fixup_kernel<<<dim3(512), dim3(256), 0, stream>>>(Z, Cb, out, wslist, cap);
}

// Round 3
// 264.482 us; speedup vs baseline: 1.9660x; 1.9660x over previous
//
#include <hip/hip_runtime.h>
#include <math.h>

#define BQ 65536
#define NC 512
#define DD 512
#define BM 128
#define BN 256
#define BK 32
#define MARGIN 3e-3f
#define FINF 3.402823466e38f

typedef short bf16x8 __attribute__((ext_vector_type(8)));
typedef float f32x4 __attribute__((ext_vector_type(4)));

// LDS geometry: padded row stride of 20 dwords (80 B = 5*16 B) keeps
// ds_read_b128 fragment reads and uint2 staging writes at <=2-way bank
// aliasing (free per m136). Offsets in dwords:
#define AHI 0
#define ALO 2560
#define BHI 5120
#define BLO 10240
#define STRIDE 20

__device__ __forceinline__ unsigned int cvt_pk_bf16(float a, float b) {
    unsigned int r;
    asm("v_cvt_pk_bf16_f32 %0, %1, %2" : "=v"(r) : "v"(a), "v"(b));
    return r;  // low16 = bf16(a), high16 = bf16(b), RNE
}

// Split 4 consecutive fp32 into packed bf16 hi-pairs and lo-pairs.
// lo = f - f32(hi) is exact (same-exponent subtract); dropped lo*lo term
// plus lo rounding bounds dot error ~5e-5 << MARGIN.
__device__ __forceinline__ void split4(float4 v, uint2* hi, uint2* lo) {
    unsigned int h0 = cvt_pk_bf16(v.x, v.y);
    unsigned int h1 = cvt_pk_bf16(v.z, v.w);
    float hx = __uint_as_float(h0 << 16);
    float hy = __uint_as_float(h0 & 0xFFFF0000u);
    float hz = __uint_as_float(h1 << 16);
    float hw = __uint_as_float(h1 & 0xFFFF0000u);
    *hi = make_uint2(h0, h1);
    *lo = make_uint2(cvt_pk_bf16(v.x - hx, v.y - hy),
                     cvt_pk_bf16(v.z - hz, v.w - hw));
}

__device__ __forceinline__ float pw128_sq(const float* __restrict__ p) {
    float r[8];
    #pragma unroll
    for (int j = 0; j < 8; ++j) r[j] = 0.0f;
    #pragma unroll
    for (int q = 0; q < 32; ++q) {
        float4 v = *(const float4*)(p + q * 4);
        const int e = (q & 1) << 2;
        r[e + 0] = __fadd_rn(r[e + 0], __fmul_rn(v.x, v.x));
        r[e + 1] = __fadd_rn(r[e + 1], __fmul_rn(v.y, v.y));
        r[e + 2] = __fadd_rn(r[e + 2], __fmul_rn(v.z, v.z));
        r[e + 3] = __fadd_rn(r[e + 3], __fmul_rn(v.w, v.w));
    }
    return __fadd_rn(__fadd_rn(__fadd_rn(r[0], r[1]), __fadd_rn(r[2], r[3])),
                     __fadd_rn(__fadd_rn(r[4], r[5]), __fadd_rn(r[6], r[7])));
}

// Pass 1: bf16x3 split MFMA GEMM computing metric m_j = csq[j] - 2*z.c_j,
// tracking best+second-best per row; marginal rows -> fp64 fixup worklist.
__global__ __launch_bounds__(256, 2) void codebook_kernel(
    const float* __restrict__ Z, const float* __restrict__ Cb,
    float* __restrict__ out, int* __restrict__ wslist, int cap) {

    __shared__ __align__(16) unsigned int stage[15360];  // Ahi|Alo|Bhi|Blo
    __shared__ float csq[NC];
    __shared__ float red_b1[2][BM];
    __shared__ float red_b2[2][BM];
    __shared__ int   red_i1[2][BM];
    __shared__ int   bif[BM];

    const int tid = threadIdx.x;
    const int m0 = blockIdx.x * BM;
    const int l = tid & 63, wid = tid >> 6;
    const int wr0 = (wid >> 1) * 64;     // wave row base (0 or 64)
    const int wc0 = (wid & 1) * 128;     // wave col base within chunk
    const int g = l >> 4, c = l & 15;

    // csq for all 512 codes (codebook L2-resident)
    #pragma unroll
    for (int cc = 0; cc < 2; ++cc) {
        const int code = tid + cc * 256;
        const float* p = Cb + (size_t)code * DD;
        float b0 = pw128_sq(p), b1 = pw128_sq(p + 128);
        float b2 = pw128_sq(p + 256), b3 = pw128_sq(p + 384);
        csq[code] = __fadd_rn(__fadd_rn(b0, b1), __fadd_rn(b2, b3));
    }

    float rb1 = FINF, rb2 = FINF; int ri1 = 0;   // running best (tid<128)

    float4 va[4], vb[8];
    // prologue: issue loads for step 0
    #pragma unroll
    for (int p = 0; p < 4; ++p) {
        int q = tid + p * 256;
        va[p] = *(const float4*)(Z + (size_t)(m0 + (q >> 3)) * DD + (q & 7) * 4);
    }
    #pragma unroll
    for (int p = 0; p < 8; ++p) {
        int q = tid + p * 256;
        vb[p] = *(const float4*)(Cb + (size_t)(q >> 3) * DD + (q & 7) * 4);
    }

    f32x4 acc[4][8];

    for (int step = 0; step < 32; ++step) {
        const int kt = (step & 15) * BK;
        const int n0 = (step >> 4) * BN;
        if ((step & 15) == 0) {
            #pragma unroll
            for (int i = 0; i < 4; ++i)
                #pragma unroll
                for (int j = 0; j < 8; ++j) acc[i][j] = (f32x4)0.0f;
        }
        __syncthreads();   // prior MFMA frag reads done -> LDS reusable
        // convert previous loads, write to LDS
        #pragma unroll
        for (int p = 0; p < 4; ++p) {
            int q = tid + p * 256;
            int r = q >> 3, k2 = (q & 7) * 2;
            uint2 h, lo;
            split4(va[p], &h, &lo);
            *(uint2*)&stage[AHI + r * STRIDE + k2] = h;
            *(uint2*)&stage[ALO + r * STRIDE + k2] = lo;
        }
        #pragma unroll
        for (int p = 0; p < 8; ++p) {
            int q = tid + p * 256;
            int r = q >> 3, k2 = (q & 7) * 2;
            uint2 h, lo;
            split4(vb[p], &h, &lo);
            *(uint2*)&stage[BHI + r * STRIDE + k2] = h;
            *(uint2*)&stage[BLO + r * STRIDE + k2] = lo;
        }
        __syncthreads();   // tile ready
        // issue next step's loads early; HBM latency hides under MFMA
        if (step < 31) {
            const int kt2 = ((step + 1) & 15) * BK;
            const int n02 = ((step + 1) >> 4) * BN;
            #pragma unroll
            for (int p = 0; p < 4; ++p) {
                int q = tid + p * 256;
                va[p] = *(const float4*)(Z + (size_t)(m0 + (q >> 3)) * DD + kt2 + (q & 7) * 4);
            }
            #pragma unroll
            for (int p = 0; p < 8; ++p) {
                int q = tid + p * 256;
                vb[p] = *(const float4*)(Cb + (size_t)(n02 + (q >> 3)) * DD + kt2 + (q & 7) * 4);
            }
        }
        // fragment reads + 96 MFMA (hi*hi + hi*lo + lo*hi)
        bf16x8 ah[4], al[4];
        #pragma unroll
        for (int i = 0; i < 4; ++i) {
            int R = wr0 + i * 16 + c;
            ah[i] = *(bf16x8*)&stage[AHI + R * STRIDE + g * 4];
            al[i] = *(bf16x8*)&stage[ALO + R * STRIDE + g * 4];
        }
        #pragma unroll
        for (int j = 0; j < 8; ++j) {
            int C = wc0 + j * 16 + c;
            bf16x8 bh = *(bf16x8*)&stage[BHI + C * STRIDE + g * 4];
            bf16x8 bl = *(bf16x8*)&stage[BLO + C * STRIDE + g * 4];
            #pragma unroll
            for (int i = 0; i < 4; ++i) {
                acc[i][j] = __builtin_amdgcn_mfma_f32_16x16x32_bf16(ah[i], bh, acc[i][j], 0, 0, 0);
                acc[i][j] = __builtin_amdgcn_mfma_f32_16x16x32_bf16(ah[i], bl, acc[i][j], 0, 0, 0);
                acc[i][j] = __builtin_amdgcn_mfma_f32_16x16x32_bf16(al[i], bh, acc[i][j], 0, 0, 0);
            }
        }
        (void)kt;

        if ((step & 15) == 15) {
            // epilogue for this chunk: metric + per-row best/best2
            #pragma unroll
            for (int i = 0; i < 4; ++i) {
                #pragma unroll
                for (int r = 0; r < 4; ++r) {
                    float b1 = FINF, b2 = FINF; int i1 = 0;
                    #pragma unroll
                    for (int j = 0; j < 8; ++j) {
                        int code = n0 + wc0 + j * 16 + c;
                        float m = fmaf(-2.0f, acc[i][j][r], csq[code]);
                        if (m < b1) { b2 = b1; b1 = m; i1 = code; }
                        else b2 = fminf(b2, m);
                    }
                    #pragma unroll
                    for (int s = 1; s < 16; s <<= 1) {
                        float ob1 = __shfl_xor(b1, s);
                        float ob2 = __shfl_xor(b2, s);
                        int oi1 = __shfl_xor(i1, s);
                        if (ob1 < b1 || (ob1 == b1 && oi1 < i1)) {
                            b2 = fminf(b1, ob2); b1 = ob1; i1 = oi1;
                        } else {
                            b2 = fminf(b2, ob1);
                        }
                    }
                    if (c == 0) {
                        int row = wr0 + i * 16 + g * 4 + r;
                        red_b1[wid & 1][row] = b1;
                        red_b2[wid & 1][row] = b2;
                        red_i1[wid & 1][row] = i1;
                    }
                }
            }
            __syncthreads();
            if (tid < BM) {
                #pragma unroll
                for (int h = 0; h < 2; ++h) {   // ascending code order
                    float nb1 = red_b1[h][tid], nb2 = red_b2[h][tid];
                    int ni = red_i1[h][tid];
                    if (nb1 < rb1) { rb2 = fminf(rb1, nb2); rb1 = nb1; ri1 = ni; }
                    else rb2 = fminf(rb2, nb1);
                }
            }
            // next loop-top __syncthreads protects red[] reuse
        }
    }

    if (tid < BM) {
        bif[tid] = ri1;
        out[(size_t)BQ * NC + m0 + tid] = (float)ri1;
        if (rb2 - rb1 < MARGIN) {
            int slot = atomicAdd(wslist, 1);
            if (slot < cap) wslist[1 + slot] = m0 + tid;
        }
    }
    __syncthreads();

    // one_hot: 128 rows x 512 cols, coalesced float4 stores
    #pragma unroll 4
    for (int t = 0; t < 64; ++t) {
        int f4i = tid + t * 256;
        int r = f4i >> 7, c4 = f4i & 127;
        int tgt = bif[r];
        int base = c4 * 4;
        float4 v;
        v.x = (tgt == base + 0) ? 1.0f : 0.0f;
        v.y = (tgt == base + 1) ? 1.0f : 0.0f;
        v.z = (tgt == base + 2) ? 1.0f : 0.0f;
        v.w = (tgt == base + 3) ? 1.0f : 0.0f;
        *(float4*)(out + (size_t)(m0 + r) * NC + (size_t)base) = v;
    }
}

// Pass 2: fp64-exact argmin for marginal rows (matches numpy-fp64 argmin).
__global__ __launch_bounds__(256) void fixup_kernel(
    const float* __restrict__ Z, const float* __restrict__ Cb,
    float* __restrict__ out, const int* __restrict__ wslist, int cap) {

    __shared__ float zrow[DD];
    __shared__ double md[256];
    __shared__ int mi[256];
    const int tid = threadIdx.x;
    int count = wslist[0];
    if (count > cap) count = cap;

    for (int e = blockIdx.x; e < count; e += gridDim.x) {
        const int row = wslist[1 + e];
        zrow[tid] = Z[(size_t)row * DD + tid];
        zrow[tid + 256] = Z[(size_t)row * DD + 256 + tid];
        __syncthreads();

        double bb = 1e300; int bidx = 0;
        #pragma unroll
        for (int cc = 0; cc < 2; ++cc) {
            const int code = tid * 2 + cc;
            const float* cp = Cb + (size_t)code * DD;
            double dot = 0.0, cs = 0.0;
            for (int k = 0; k < DD; k += 4) {
                float4 c4 = *(const float4*)(cp + k);
                double a0 = (double)zrow[k + 0], c0 = (double)c4.x;
                double a1 = (double)zrow[k + 1], c1 = (double)c4.y;
                double a2 = (double)zrow[k + 2], c2 = (double)c4.z;
                double a3 = (double)zrow[k + 3], c3 = (double)c4.w;
                dot = fma(a0, c0, dot); cs = fma(c0, c0, cs);
                dot = fma(a1, c1, dot); cs = fma(c1, c1, cs);
                dot = fma(a2, c2, dot); cs = fma(c2, c2, cs);
                dot = fma(a3, c3, dot); cs = fma(c3, c3, cs);
            }
            double m = cs - 2.0 * dot;
            if (m < bb || (m == bb && code < bidx)) { bb = m; bidx = code; }
        }
        md[tid] = bb; mi[tid] = bidx;
        __syncthreads();
        for (int s = 128; s > 0; s >>= 1) {
            if (tid < s) {
                if (md[tid + s] < md[tid] ||
                    (md[tid + s] == md[tid] && mi[tid + s] < mi[tid])) {
                    md[tid] = md[tid + s]; mi[tid] = mi[tid + s];
                }
            }
            __syncthreads();
        }
        const int imin = mi[0];
        out[(size_t)row * NC + tid] = (tid == imin) ? 1.0f : 0.0f;
        out[(size_t)row * NC + 256 + tid] = (tid + 256 == imin) ? 1.0f : 0.0f;
        if (tid == 0) out[(size_t)BQ * NC + row] = (float)imin;
        __syncthreads();
    }
}

extern "C" void kernel_launch(void* const* d_in, const int* in_sizes, int n_in,
                              void* d_out, int out_size, void* d_ws, size_t ws_size,
                              hipStream_t stream) {
    const float* Z = (const float*)d_in[0];
    const float* Cb = (const float*)d_in[1];
    float* out = (float*)d_out;
    int* wslist = (int*)d_ws;
    int cap = (int)(ws_size / 4) - 1;
    if (cap > BQ) cap = BQ;
    hipMemsetAsync(d_ws, 0, 4, stream);
    codebook_kernel<<<dim3(BQ / BM), dim3(256), 0, stream>>>(Z, Cb, out, wslist, cap);
    fixup_kernel<<<dim3(512), dim3(256), 0, stream>>>(Z, Cb, out, wslist, cap);
}